// Round 1
// baseline (7832.095 us; speedup 1.0000x reference)
//
#include <hip/hip_runtime.h>
#include <stdint.h>

#define NPER 8192
#define NB 4
#define MPER 4096
#define MTOT (NB*MPER)      // 16384
#define KNB 64
#define CIN 64
#define R2C 0.04f           // f32-nearest of python 0.2*0.2 (NOT 0.2f*0.2f!)

// d_out (floats): x_out [MTOT*128] | pos_out [MTOT*3] | batch_out [MTOT]
#define POSOUT_OFF (MTOT*128)
#define BATCH_OFF  (MTOT*128 + MTOT*3)

// ws: nbr u16 [MTOT*64] @0 (2MB) | cnt i32 [MTOT] @2MB (64KB)

// ---------------------------------------------------------------- K1: FPS
// One block per cloud (serial algorithm). 512 thr, 16 pts/thread in registers.
// d2 computed bitwise-identical to numpy: subs/muls/adds, sum order ((x+y)+z),
// no fma. Argmax = max-only reduce, then exact-equality claim + atomicMin on
// packed (idx<<32|coord-bits) -> first-max tie-break like np.argmax, and the
// winning point's coords are published without a global-memory lookup.
__global__ __launch_bounds__(512) void k_fps(const float* __restrict__ pos,
                                             float* __restrict__ dout)
{
  const int b = blockIdx.x;
  const int tid = threadIdx.x;
  const float* pb = pos + (size_t)b * NPER * 3;
  float* qo = dout + POSOUT_OFF + (size_t)b * MPER * 3;

  __shared__ float warr[8];
  __shared__ unsigned long long pk[2][3];   // double-buffered claim slots

  float X[16], Y[16], Z[16], D[16];
#pragma unroll
  for (int k = 0; k < 16; ++k) {
    int i = tid + (k << 9);
    X[k] = pb[i*3+0]; Y[k] = pb[i*3+1]; Z[k] = pb[i*3+2];
    D[k] = 3.402823466e+38f;
  }
  if (tid == 0) {
    // seed: point 0 (idx 0); tid0's k=0 slot IS point 0
    pk[0][0] = ((unsigned long long)0u << 32) | __float_as_uint(X[0]);
    pk[0][1] = ((unsigned long long)0u << 32) | __float_as_uint(Y[0]);
    pk[0][2] = ((unsigned long long)0u << 32) | __float_as_uint(Z[0]);
    pk[1][0] = ~0ull; pk[1][1] = ~0ull; pk[1][2] = ~0ull;
  }
  __syncthreads();

  for (int m = 1; m < MPER; ++m) {
    const int rb = (m-1) & 1, wb = m & 1;
    unsigned long long p0 = pk[rb][0], p1 = pk[rb][1], p2 = pk[rb][2];
    float nx = __uint_as_float((unsigned)p0);
    float ny = __uint_as_float((unsigned)p1);
    float nz = __uint_as_float((unsigned)p2);
    if (tid == 0) {  // output row m-1 (selection made last iter; m=1 -> seed)
      qo[(m-1)*3+0] = nx; qo[(m-1)*3+1] = ny; qo[(m-1)*3+2] = nz;
    }
    float lv = 0.0f;
#pragma unroll
    for (int k = 0; k < 16; ++k) {
      float dx = __fsub_rn(X[k], nx);
      float dy = __fsub_rn(Y[k], ny);
      float dz = __fsub_rn(Z[k], nz);
      float s = __fadd_rn(__fadd_rn(__fmul_rn(dx,dx), __fmul_rn(dy,dy)),
                          __fmul_rn(dz,dz));
      D[k] = fminf(D[k], s);
      lv = fmaxf(lv, D[k]);
    }
    float wv = lv;
#pragma unroll
    for (int off = 1; off < 64; off <<= 1)
      wv = fmaxf(wv, __shfl_xor(wv, off));
    if ((tid & 63) == 0) warr[tid >> 6] = wv;
    __syncthreads();
    float gm = warr[0];
#pragma unroll
    for (int w = 1; w < 8; ++w) gm = fmaxf(gm, warr[w]);
    // reset read-buffer for iter m+1's claims (reads of it finished pre-barrier)
    if (tid == 0) { pk[rb][0] = ~0ull; pk[rb][1] = ~0ull; pk[rb][2] = ~0ull; }
    if (lv == gm) {          // exact: gm is fmax over exactly these values
#pragma unroll
      for (int k = 0; k < 16; ++k) {
        if (D[k] == gm) {
          unsigned long long hi =
            ((unsigned long long)(unsigned)(tid + (k << 9))) << 32;
          atomicMin(&pk[wb][0], hi | __float_as_uint(X[k]));
          atomicMin(&pk[wb][1], hi | __float_as_uint(Y[k]));
          atomicMin(&pk[wb][2], hi | __float_as_uint(Z[k]));
          break;               // first (smallest-idx) match in this thread
        }
      }
    }
    __syncthreads();
  }
  if (tid == 0) {              // last selection (m = MPER-1)
    unsigned long long p0 = pk[(MPER-1)&1][0];
    unsigned long long p1 = pk[(MPER-1)&1][1];
    unsigned long long p2 = pk[(MPER-1)&1][2];
    qo[(MPER-1)*3+0] = __uint_as_float((unsigned)p0);
    qo[(MPER-1)*3+1] = __uint_as_float((unsigned)p1);
    qo[(MPER-1)*3+2] = __uint_as_float((unsigned)p2);
  }
}

// ------------------------------------------------- K2: radius + top-K select
// One wave per centroid. Candidates (d2<=R2) appended via ballot-prefix into
// LDS as u64 key = (d2_bits<<32)|idx (d2>=0 so float bits are order-monotone;
// idx in low bits reproduces top_k's lower-index tie-break). Bitonic sort 512.
#define SCAP 512
__global__ __launch_bounds__(256) void k_radius(const float* __restrict__ pos,
    float* __restrict__ dout, unsigned short* __restrict__ nbr,
    int* __restrict__ cnt)
{
  __shared__ unsigned long long cand[4][SCAP];
  const int wid = threadIdx.x >> 6, lane = threadIdx.x & 63;
  const int m = blockIdx.x * 4 + wid;
  const int b = m >> 12;
  const float* pb = pos + (size_t)b * NPER * 3;
  const float* q = dout + POSOUT_OFF + (size_t)m * 3;
  const float qx = q[0], qy = q[1], qz = q[2];
  unsigned cw = 0;
  for (int it = 0; it < NPER/64; ++it) {
    int i = (it << 6) + lane;
    float dx = __fsub_rn(qx, pb[i*3+0]);
    float dy = __fsub_rn(qy, pb[i*3+1]);
    float dz = __fsub_rn(qz, pb[i*3+2]);
    float d2 = __fadd_rn(__fadd_rn(__fmul_rn(dx,dx), __fmul_rn(dy,dy)),
                         __fmul_rn(dz,dz));
    bool in = (d2 <= R2C);
    unsigned long long mk = __ballot(in);
    unsigned pre = (unsigned)__popcll(mk & ((1ull << lane) - 1ull));
    if (in) {
      unsigned slot = cw + pre;
      if (slot < SCAP)
        cand[wid][slot] =
          (((unsigned long long)__float_as_uint(d2)) << 32) | (unsigned)i;
    }
    cw += (unsigned)__popcll(mk);
  }
  if (cw > SCAP) cw = SCAP;   // statistically unreachable (lambda_max ~274)
  for (int s = (int)cw + lane; s < SCAP; s += 64) cand[wid][s] = ~0ull;
  __syncthreads();
  for (int k = 2; k <= SCAP; k <<= 1) {
    for (int j = k >> 1; j > 0; j >>= 1) {
#pragma unroll
      for (int s = 0; s < SCAP/128; ++s) {
        int t = lane + (s << 6);
        int e = ((t & ~(j-1)) << 1) | (t & (j-1));
        int p = e | j;
        unsigned long long a = cand[wid][e], c = cand[wid][p];
        bool asc = ((e & k) == 0);
        bool sw = asc ? (a > c) : (a < c);
        if (sw) { cand[wid][e] = c; cand[wid][p] = a; }
      }
      __syncthreads();
    }
  }
  int kk = (int)cw; if (kk > KNB) kk = KNB;
  unsigned long long key = cand[wid][lane];
  nbr[(size_t)m*KNB + lane] =
    (lane < kk) ? (unsigned short)(key & 0xFFFFull) : (unsigned short)0;
  if (lane == 0) {
    cnt[m] = kk;
    dout[BATCH_OFF + m] = (float)b;   // batch_out (buffer read as f32)
  }
}

// --------------------------------------------- K3: gather -> MLP -> max (fp32)
// One 128-thr block per centroid. featT[ch][j] (stride 68) + W1 in LDS;
// stage B: 8j x 4h register tile; h1T reuses featT buffer; W2 streamed in
// 16-row chunks through the W1 buffer; stage C: 8j x 8c tile; masked
// shuffle-max over j, write 128 outputs.
__global__ __launch_bounds__(128) void k_conv(
    const float* __restrict__ x, const float* __restrict__ pos,
    const float* __restrict__ W1, const float* __restrict__ b1,
    const float* __restrict__ W2, const float* __restrict__ b2,
    const unsigned short* __restrict__ nbr, const int* __restrict__ cntp,
    float* __restrict__ dout)
{
  __shared__ __align__(16) float bufA[68*68];   // featT then h1T (stride 68)
  __shared__ __align__(16) float bufB[68*68];   // W1 then W2 chunks (str 136)
  __shared__ unsigned short nbr_s[64];
  __shared__ float qv[3];
  __shared__ int cnt_s;
  const int t = threadIdx.x;
  const int m = blockIdx.x;
  const int b = m >> 12;
  if (t < 64) nbr_s[t] = nbr[(size_t)m*KNB + t];
  else if (t == 64) cnt_s = cntp[m];
  else if (t >= 65 && t < 68) qv[t-65] = dout[POSOUT_OFF + (size_t)m*3 + (t-65)];
  for (int e = t; e < 67*64; e += 128) {
    int ch = e >> 6, h = e & 63;
    bufB[ch*68 + h] = W1[e];
  }
  __syncthreads();
  {                                   // gather x rows -> featT rows 0..63
    const int ch = t & 63, jj = t >> 6;
    const size_t xb = (size_t)b * NPER * CIN;
    for (int j0 = 0; j0 < 64; j0 += 2) {
      int j = j0 + jj;
      int r = nbr_s[j];
      bufA[ch*68 + j] = x[xb + (size_t)r*CIN + ch];
    }
  }
  {                                   // rel -> rows 64..66
    const size_t pbb = (size_t)b * NPER * 3;
    for (int e = t; e < 192; e += 128) {
      int j = e & 63, d = e >> 6;
      int r = nbr_s[j];
      bufA[(64+d)*68 + j] = pos[pbb + (size_t)r*3 + d] - qv[d];
    }
  }
  __syncthreads();

  const int jg = t & 7, hg = t >> 3;
  const int j0 = jg << 3;
  const int h0 = hg << 2;
  float acc[4][8];
#pragma unroll
  for (int hh = 0; hh < 4; ++hh)
#pragma unroll
    for (int j = 0; j < 8; ++j) acc[hh][j] = 0.0f;
  for (int ch = 0; ch < 67; ++ch) {
    const float4 fa = *(const float4*)&bufA[ch*68 + j0];
    const float4 fb = *(const float4*)&bufA[ch*68 + j0 + 4];
    const float4 w  = *(const float4*)&bufB[ch*68 + h0];
    const float ws4[4] = {w.x, w.y, w.z, w.w};
    const float fj[8] = {fa.x, fa.y, fa.z, fa.w, fb.x, fb.y, fb.z, fb.w};
#pragma unroll
    for (int hh = 0; hh < 4; ++hh)
#pragma unroll
      for (int j = 0; j < 8; ++j)
        acc[hh][j] += ws4[hh] * fj[j];
  }
  __syncthreads();                    // featT + W1 reads complete
  {                                   // h1T = relu(acc + b1) into bufA
    const float4 bb = *(const float4*)&b1[h0];
    const float bv[4] = {bb.x, bb.y, bb.z, bb.w};
#pragma unroll
    for (int hh = 0; hh < 4; ++hh) {
      float4 o0, o1;
      o0.x = fmaxf(acc[hh][0] + bv[hh], 0.0f);
      o0.y = fmaxf(acc[hh][1] + bv[hh], 0.0f);
      o0.z = fmaxf(acc[hh][2] + bv[hh], 0.0f);
      o0.w = fmaxf(acc[hh][3] + bv[hh], 0.0f);
      o1.x = fmaxf(acc[hh][4] + bv[hh], 0.0f);
      o1.y = fmaxf(acc[hh][5] + bv[hh], 0.0f);
      o1.z = fmaxf(acc[hh][6] + bv[hh], 0.0f);
      o1.w = fmaxf(acc[hh][7] + bv[hh], 0.0f);
      *(float4*)&bufA[(h0+hh)*68 + j0] = o0;
      *(float4*)&bufA[(h0+hh)*68 + j0 + 4] = o1;
    }
  }
  const int c0 = hg << 3;             // stage C: 8j x 8c
  float acc2[8][8];                   // [c][j]
#pragma unroll
  for (int c = 0; c < 8; ++c)
#pragma unroll
    for (int j = 0; j < 8; ++j) acc2[c][j] = 0.0f;
  for (int hc = 0; hc < 64; hc += 16) {
    __syncthreads();                  // h1T ready / prior chunk consumed
    for (int e = t; e < 16*128; e += 128) {
      int hh = e >> 7, c = e & 127;
      bufB[hh*136 + c] = W2[(size_t)(hc+hh)*128 + c];
    }
    __syncthreads();
#pragma unroll
    for (int h = 0; h < 16; ++h) {
      const float4 ja = *(const float4*)&bufA[(hc+h)*68 + j0];
      const float4 jb = *(const float4*)&bufA[(hc+h)*68 + j0 + 4];
      const float4 wa = *(const float4*)&bufB[h*136 + c0];
      const float4 wb = *(const float4*)&bufB[h*136 + c0 + 4];
      const float hv[8] = {ja.x, ja.y, ja.z, ja.w, jb.x, jb.y, jb.z, jb.w};
      const float wv[8] = {wa.x, wa.y, wa.z, wa.w, wb.x, wb.y, wb.z, wb.w};
#pragma unroll
      for (int c = 0; c < 8; ++c)
#pragma unroll
        for (int j = 0; j < 8; ++j)
          acc2[c][j] += wv[c] * hv[j];
    }
  }
  const int cntv = cnt_s;
  const float4 b2a = *(const float4*)&b2[c0];
  const float4 b2b = *(const float4*)&b2[c0 + 4];
  const float bv2[8] = {b2a.x, b2a.y, b2a.z, b2a.w, b2b.x, b2b.y, b2b.z, b2b.w};
  float best[8];
#pragma unroll
  for (int c = 0; c < 8; ++c) {
    float v = -3.402823466e+38f;
#pragma unroll
    for (int j = 0; j < 8; ++j) {
      float hv = fmaxf(acc2[c][j] + bv2[c], 0.0f);
      v = (j0 + j < cntv) ? fmaxf(v, hv) : v;
    }
    best[c] = v;
  }
#pragma unroll
  for (int off = 1; off < 8; off <<= 1)
#pragma unroll
    for (int c = 0; c < 8; ++c)
      best[c] = fmaxf(best[c], __shfl_xor(best[c], off));
  if (jg == 0) {
    float4 o0 = {best[0], best[1], best[2], best[3]};
    float4 o1 = {best[4], best[5], best[6], best[7]};
    *(float4*)&dout[(size_t)m*128 + c0] = o0;
    *(float4*)&dout[(size_t)m*128 + c0 + 4] = o1;
  }
}

extern "C" void kernel_launch(void* const* d_in, const int* in_sizes, int n_in,
                              void* d_out, int out_size, void* d_ws, size_t ws_size,
                              hipStream_t stream) {
  const float* x   = (const float*)d_in[0];
  const float* pos = (const float*)d_in[1];
  // d_in[2] = batch (layout known statically, unused)
  const float* W1  = (const float*)d_in[3];
  const float* b1  = (const float*)d_in[4];
  const float* W2  = (const float*)d_in[5];
  const float* b2  = (const float*)d_in[6];
  float* dout = (float*)d_out;
  unsigned short* nbr = (unsigned short*)d_ws;
  int* cnt = (int*)((char*)d_ws + (size_t)MTOT*KNB*2);

  hipLaunchKernelGGL(k_fps,    dim3(NB),     dim3(512), 0, stream, pos, dout);
  hipLaunchKernelGGL(k_radius, dim3(MTOT/4), dim3(256), 0, stream, pos, dout, nbr, cnt);
  hipLaunchKernelGGL(k_conv,   dim3(MTOT),   dim3(128), 0, stream,
                     x, pos, W1, b1, W2, b2, nbr, cnt, dout);
}